// Round 20
// baseline (269.318 us; speedup 1.0000x reference)
//
#include <hip/hip_runtime.h>
#include <hip/hip_bf16.h>
#include <stdint.h>

// MLA forward, bf16 MFMA pipeline. Prefill-optimal DECOMPRESSED attention:
// K_h = [kvn @ wkvb_nope^T | rope(k_pe)] (192-dim), V2T_h = wkvb_v @ kvn^T.
// Attention: fused flash kernel, KVBLK=64, Kn dbuf XOR-swizzled in LDS,
// rope K and V2T read direct from global (L2-resident, issued early),
// defer-rescale online softmax, head-parity qb pairing, 3 blocks/CU (41KB LDS).
// Shapes: B=1 S=2048 HID=2048 H=16 QLR=1536 KVLR=512 NOPE=128 ROPE=64 VD=128 QKD=192.

using bf16 = __hip_bfloat16;
typedef __bf16 bf16x8 __attribute__((ext_vector_type(8)));
typedef __bf16 bf16x4 __attribute__((ext_vector_type(4)));
typedef float f32x4 __attribute__((ext_vector_type(4)));

#define S_LEN 2048
#define NHEAD 16

static __device__ __forceinline__ void gload16(const void* g, void* l) {
  __builtin_amdgcn_global_load_lds(
      (const __attribute__((address_space(1))) unsigned int*)g,
      (__attribute__((address_space(3))) unsigned int*)l, 16, 0, 0);
}

// ---------------- fused fp32 -> bf16 converts (all 6 tensors, 1 launch) -----
__global__ void cvt_all(const float* __restrict__ x, const float* __restrict__ wqa_s,
                        const float* __restrict__ wqb_s, const float* __restrict__ wkva_s,
                        const float* __restrict__ wkvb_s, const float* __restrict__ wo_s,
                        bf16* __restrict__ xb, bf16* __restrict__ wqa,
                        bf16* __restrict__ wqb, bf16* __restrict__ wkva,
                        bf16* __restrict__ wkvb, bf16* __restrict__ wob) {
  // segment sizes in float4 units
  const size_t n0 = 1048576;           // x     2048x2048
  const size_t n1 = n0 + 786432;       // wq_a  1536x2048
  const size_t n2 = n1 + 1179648;      // wq_b  3072x1536
  const size_t n3 = n2 + 327680;       // wkv_a 576x2048 padded to 640 rows
  const size_t n4 = n3 + 524288;       // wkv_b 4096x512
  const size_t n5 = n4 + 1048576;      // wo    2048x2048
  auto cvt4 = [](const float4 v, bf16* d) {
    bf16x4 o;
    o[0] = (__bf16)__float2bfloat16(v.x);
    o[1] = (__bf16)__float2bfloat16(v.y);
    o[2] = (__bf16)__float2bfloat16(v.z);
    o[3] = (__bf16)__float2bfloat16(v.w);
    *(bf16x4*)d = o;
  };
  for (size_t i = (size_t)blockIdx.x * blockDim.x + threadIdx.x; i < n5;
       i += (size_t)gridDim.x * blockDim.x) {
    if (i < n0) {
      cvt4(*(const float4*)(x + i * 4), xb + i * 4);
    } else if (i < n1) {
      size_t j = i - n0;
      cvt4(*(const float4*)(wqa_s + j * 4), wqa + j * 4);
    } else if (i < n2) {
      size_t j = i - n1;
      cvt4(*(const float4*)(wqb_s + j * 4), wqb + j * 4);
    } else if (i < n3) {
      size_t j = i - n2;
      size_t e = j * 4;
      int r = (int)(e / 2048), c = (int)(e % 2048);
      float4 v = (r < 576) ? *(const float4*)(wkva_s + (size_t)r * 2048 + c)
                           : make_float4(0.f, 0.f, 0.f, 0.f);
      cvt4(v, wkva + e);
    } else if (i < n4) {
      size_t j = i - n3;
      cvt4(*(const float4*)(wkvb_s + j * 4), wkvb + j * 4);
    } else {
      size_t j = i - n4;
      cvt4(*(const float4*)(wo_s + j * 4), wob + j * 4);
    }
  }
}

// ---------------- row RMSNorm (bf16 in -> bf16 out) -------------------------
__global__ void rmsnorm_bf16(const bf16* __restrict__ in, const float* __restrict__ w,
                             bf16* __restrict__ out, int cols) {
  const int r = blockIdx.x, tid = threadIdx.x;
  const bf16* row = in + (size_t)r * cols;
  float ss = 0.f;
  for (int c = tid; c < cols; c += 256) {
    float v = __bfloat162float(row[c]);
    ss += v * v;
  }
  for (int m = 32; m >= 1; m >>= 1) ss += __shfl_xor(ss, m, 64);
  __shared__ float red[4];
  if ((tid & 63) == 0) red[tid >> 6] = ss;
  __syncthreads();
  ss = red[0] + red[1] + red[2] + red[3];
  float inv = rsqrtf(ss / (float)cols + 1e-6f);
  for (int c = tid; c < cols; c += 256)
    out[(size_t)r * cols + c] = __float2bfloat16(__bfloat162float(row[c]) * inv * w[c]);
}

// ---- kv post: rmsnorm(kv) -> kvn[t][512]; rope(k_pe) -> Kh[h][t][128..192) --
__global__ void kv_post(const float* __restrict__ kvf, const float* __restrict__ kvw,
                        bf16* __restrict__ kvn, bf16* __restrict__ Kh) {
  const int t = blockIdx.x, tid = threadIdx.x;
  const float* row = kvf + (size_t)t * 640;
  float ss = 0.f;
  for (int c = tid; c < 512; c += 256) { float v = row[c]; ss += v * v; }
  for (int m = 32; m >= 1; m >>= 1) ss += __shfl_xor(ss, m, 64);
  __shared__ float red[4];
  if ((tid & 63) == 0) red[tid >> 6] = ss;
  __syncthreads();
  ss = red[0] + red[1] + red[2] + red[3];
  float inv = rsqrtf(ss * (1.0f / 512.0f) + 1e-6f);
  for (int c = tid; c < 512; c += 256)
    kvn[(size_t)t * 512 + c] = __float2bfloat16(row[c] * inv * kvw[c]);
  if (tid < 32) {
    const int j = tid;
    float freq = expf(-(float)j * (1.0f / 32.0f) * 9.210340371976184f); // ln(10000)
    float ang = (float)t * freq;
    float cs = cosf(ang), sn = sinf(ang);
    float x1 = row[512 + j];
    float x2 = row[512 + j + 32];
    bf16 o1 = __float2bfloat16(x1 * cs - x2 * sn);
    bf16 o2 = __float2bfloat16(x2 * cs + x1 * sn);
#pragma unroll
    for (int h = 0; h < 16; ++h) {
      bf16* kr = Kh + ((size_t)h * S_LEN + t) * 192 + 128;
      kr[j] = o1;
      kr[j + 32] = o2;
    }
  }
}

// ---------------- q rope, in-place on qv[s][h*192+128 .. +192) --------------
__global__ void q_rope(bf16* __restrict__ qv) {
  const int s = blockIdx.x, tid = threadIdx.x;
  for (int it = tid; it < 512; it += 256) {
    const int h = it >> 5, j = it & 31;
    float freq = expf(-(float)j * (1.0f / 32.0f) * 9.210340371976184f);
    float ang = (float)s * freq;
    float cs = cosf(ang), sn = sinf(ang);
    bf16* base = qv + (size_t)s * 3072 + h * 192 + 128;
    float x1 = __bfloat162float(base[j]);
    float x2 = __bfloat162float(base[j + 32]);
    base[j] = __float2bfloat16(x1 * cs - x2 * sn);
    base[j + 32] = __float2bfloat16(x2 * cs + x1 * sn);
  }
}

// ---------------- fused flash attention (decompressed heads) ----------------
// grid (32 qb, 16 h) swizzled 8-XCD; 256 thr = 4 waves; wave w owns q rows
// qb*64+w*16..+16. KVBLK=64. LDS: Kn[2][64x128] XOR-swizzled dbuf + Pl[4][16x72]
// = 41KB -> 3 blocks/CU (12 waves/CU). Rope K and V (V2T) read direct from
// global (L2-resident; V issued early, covered by QK+softmax). Single
// barrier/tile. Head-parity qb pairing balances CU work (33 tiles each).
__global__ __launch_bounds__(256, 3)
void attn_flash(const bf16* __restrict__ qv, const bf16* __restrict__ Kh,
                const bf16* __restrict__ V2T, bf16* __restrict__ oabs) {
  const int lin = (int)blockIdx.x + 32 * (int)blockIdx.y;
  const int l2 = (lin & 7) * 64 + (lin >> 3);   // 512 blocks, 64 per XCD
  const int h = l2 >> 5;
  const int idx = l2 & 31;
  const int qb = (h & 1) ? idx : 31 - idx;      // heavy+light pairing per CU
  const int tid = threadIdx.x, w = tid >> 6, lane = tid & 63;
  const int lo = lane & 15, hi = lane >> 4;
  __shared__ bf16 Kn[2][64 * 128];   // 32 KB
  __shared__ bf16 Pl[4][16 * 72];    //  9 KB
  const int q0 = qb * 64 + w * 16;
  const int q = q0 + lo;

  // persistent Q fragments (lane lo = q col, hi*8 = k offset)
  bf16x8 Qf[6];
  {
    const bf16* qp = qv + (size_t)(q0 + lo) * 3072 + h * 192 + hi * 8;
#pragma unroll
    for (int ks = 0; ks < 6; ++ks) Qf[ks] = *(const bf16x8*)(qp + ks * 32);
  }
  f32x4 o[8];
#pragma unroll
  for (int cg = 0; cg < 8; ++cg) o[cg] = (f32x4){0.f, 0.f, 0.f, 0.f};
  float mrow = -3e38f, lrow = 0.f;

  const bf16* khh = Kh + (size_t)h * S_LEN * 192;
  const bf16* vth = V2T + (size_t)h * 128 * S_LEN + (size_t)lo * 2048 + hi * 8;

  // stage Kn tile tt into buffer b (linear LDS dest, inverse-swizzled source)
  auto stage = [&](int tt, int b) {
    const int t0s = tt * 64;
#pragma unroll
    for (int i = 0; i < 4; ++i) {            // Kn: 16 calls (4/wave), 4 rows each
      const int c = w * 4 + i;
      const int row = c * 4 + (lane >> 4);
      gload16(khh + (size_t)(t0s + row) * 192 + (((lane & 15) ^ (row & 7)) << 3),
              &Kn[b][c * 512]);
    }
  };

  const int ntile = qb + 1;
  stage(0, 0);
  for (int t = 0; t < ntile; ++t) {
    __syncthreads();  // own gload16s drained; tile t visible to all
    const int b = t & 1;
    const int t0 = t * 64;

    // V fragments tk=0 direct from global (used last; latency under QK+softmax)
    bf16x8 vf0[8];
#pragma unroll
    for (int cg = 0; cg < 8; ++cg)
      vf0[cg] = *(const bf16x8*)(vth + (size_t)cg * 32768 + t0);

    // rope K fragments direct from global (used after nope QK)
    bf16x8 rk[2][4];
#pragma unroll
    for (int ks2 = 0; ks2 < 2; ++ks2)
#pragma unroll
      for (int f = 0; f < 4; ++f)
        rk[ks2][f] = *(const bf16x8*)(khh + (size_t)(t0 + f * 16 + lo) * 192 + 128 +
                                      ks2 * 32 + hi * 8);

    if (t + 1 < ntile) stage(t + 1, b ^ 1);

    // ---- S^T = K · Q  (A = K rows t, B = Q cols q); nope from LDS, rope regs
    f32x4 sc[4];
#pragma unroll
    for (int f = 0; f < 4; ++f) sc[f] = (f32x4){0.f, 0.f, 0.f, 0.f};
#pragma unroll
    for (int ks = 0; ks < 4; ++ks)
#pragma unroll
      for (int f = 0; f < 4; ++f) {
        const int row = f * 16 + lo;
        bf16x8 kf = *(const bf16x8*)&Kn[b][row * 128 + ((((ks << 2) + hi) ^ (row & 7)) << 3)];
        sc[f] = __builtin_amdgcn_mfma_f32_16x16x32_bf16(kf, Qf[ks], sc[f], 0, 0, 0);
      }

    // V fragments tk=1 (issued mid-tile, used at PV end)
    bf16x8 vf1[8];
#pragma unroll
    for (int cg = 0; cg < 8; ++cg)
      vf1[cg] = *(const bf16x8*)(vth + (size_t)cg * 32768 + t0 + 32);

#pragma unroll
    for (int ks2 = 0; ks2 < 2; ++ks2)
#pragma unroll
      for (int f = 0; f < 4; ++f)
        sc[f] = __builtin_amdgcn_mfma_f32_16x16x32_bf16(rk[ks2][f], Qf[4 + ks2], sc[f], 0, 0, 0);

    // ---- mask + scale + row max (lane-local row q = q0 + lo)
    const bool diag = (t == qb);
    float rmax = -3e38f;
#pragma unroll
    for (int f = 0; f < 4; ++f)
#pragma unroll
      for (int j = 0; j < 4; ++j) {
        float v = sc[f][j] * 0.0721687836487032f;  // 1/sqrt(192)
        if (diag && (t0 + f * 16 + hi * 4 + j > q)) v = -3e38f;
        sc[f][j] = v;
        rmax = fmaxf(rmax, v);
      }
    rmax = fmaxf(rmax, __shfl_xor(rmax, 16, 64));
    rmax = fmaxf(rmax, __shfl_xor(rmax, 32, 64));

    // ---- defer-rescale: only when the running max actually grows
    if (!__all(rmax <= mrow)) {
      const float mn = fmaxf(mrow, rmax);
      const float fsc = __expf(mrow - mn);
      mrow = mn;
      lrow *= fsc;
      float fscO[4];
#pragma unroll
      for (int j = 0; j < 4; ++j) fscO[j] = __shfl(fsc, hi * 4 + j, 64);
#pragma unroll
      for (int cg = 0; cg < 8; ++cg)
#pragma unroll
        for (int j = 0; j < 4; ++j) o[cg][j] *= fscO[j];
    }

    // ---- P = exp(v - mrow) -> Pl (bf16 pairs), rsum
    float rsum = 0.f;
    bf16* prow = &Pl[w][lo * 72];
#pragma unroll
    for (int f = 0; f < 4; ++f) {
      float pj[4];
#pragma unroll
      for (int j = 0; j < 4; ++j) {
        pj[j] = __expf(sc[f][j] - mrow);
        rsum += pj[j];
      }
#pragma unroll
      for (int i2 = 0; i2 < 2; ++i2) {
        uint32_t lo16 = (uint32_t)__bfloat16_as_ushort(__float2bfloat16(pj[i2 * 2]));
        uint32_t hi16 = (uint32_t)__bfloat16_as_ushort(__float2bfloat16(pj[i2 * 2 + 1]));
        *(uint32_t*)(prow + f * 16 + hi * 4 + i2 * 2) = lo16 | (hi16 << 16);
      }
    }
    rsum += __shfl_xor(rsum, 16, 64);
    rsum += __shfl_xor(rsum, 32, 64);
    lrow += rsum;

    // ---- PV: pa from own wave's Pl, V from registers (global-loaded)
#pragma unroll
    for (int tk = 0; tk < 2; ++tk) {
      bf16x8 pa = *(const bf16x8*)&Pl[w][lo * 72 + tk * 32 + hi * 8];
#pragma unroll
      for (int cg = 0; cg < 8; ++cg)
        o[cg] = __builtin_amdgcn_mfma_f32_16x16x32_bf16(
            pa, (tk == 0) ? vf0[cg] : vf1[cg], o[cg], 0, 0, 0);
    }
  }

  // ---- epilogue: normalize by 1/lrow (per q row) and store
  const float linv = 1.0f / lrow;
  float linvO[4];
#pragma unroll
  for (int j = 0; j < 4; ++j) linvO[j] = __shfl(linv, hi * 4 + j, 64);
  bf16* ob = oabs + (size_t)q0 * 2048 + h * 128;
#pragma unroll
  for (int j = 0; j < 4; ++j)
#pragma unroll
    for (int cg = 0; cg < 8; ++cg)
      ob[(size_t)(hi * 4 + j) * 2048 + cg * 16 + lo] =
          __float2bfloat16(o[cg][j] * linvO[j]);
}

// ---------------- GEMM: C[m][n] = sum_k A[m][k]*B[n][k] (+bias[n]) ----------
// BM x 128 tile, 4 waves (256 thr) both variants.
//   BM=128: wave = 64x64 quadrant (acc[4][4]), 64KB LDS, 2 blocks/CU.
//   BM=64:  wave = 64x32 column stripe (acc[4][2]), 48KB LDS, 3 blocks/CU.
// BK=64, mfma 16x16x32, double-buffered LDS, prefetch-before-compute, ONE
// barrier per k-step. T2 XOR-swizzle on LDS. XCD-aware bijective swizzle.
template <bool BIAS, bool BF16OUT, int BM>
__global__ __launch_bounds__(256)
void gemm_bt(const bf16* __restrict__ A, const bf16* __restrict__ B,
             const float* __restrict__ bias, void* __restrict__ Cv,
             int lda, int ldb, int ldc, int K, int Nreal,
             long long bA, long long bB, long long bC, int mode) {
  // XCD swizzle: contiguous tile-chunk per XCD
  int bx, byi, bz;
  {
    const int gx = gridDim.x, gy = gridDim.y;
    const int nwg = gx * gy * (int)gridDim.z;
    const int lin = (int)blockIdx.x + gx * ((int)blockIdx.y + gy * (int)blockIdx.z);
    const int cpx = nwg >> 3;
    const int l2 = (lin & 7) * cpx + (lin >> 3);
    bx = l2 % gx;
    byi = (l2 / gx) % gy;
    bz = l2 / (gx * gy);
    if (mode) byi = (bz & 1) ? byi : gy - 1 - byi;
  }
  const size_t m0 = (size_t)byi * BM, n0 = (size_t)bx * 128;
  if (mode == 1 && (int)n0 >= (int)m0 + BM) return;
  const int Keff = (mode == 2) ? ((K < (int)m0 + BM) ? K : (int)m0 + BM) : K;

  constexpr int ACH = BM / 8;                  // A 1KB chunks
  constexpr int PER = (ACH + 16) / 4;          // chunks per wave (6 or 8)
  constexpr int NFR = (BM == 64) ? 2 : 4;      // n fragments per wave
  __shared__ bf16 As[2][BM * 64];
  __shared__ bf16 Bs[2][8192];
  const int tid = threadIdx.x;
  const int wave = tid >> 6, lane = tid & 63;
  const int lo = lane & 15, hi = lane >> 4;
  const int rowbase = (BM == 64) ? 0 : ((wave >> 1) * 64);
  const int colbase = (BM == 64) ? (wave * 32) : ((wave & 1) * 64);
  A += (size_t)bz * (size_t)bA;
  B += (size_t)bz * (size_t)bB;
  const int srow = lane >> 3;                        // 0..7 (also row&7)
  const int scol = (((lane & 7) ^ srow) * 8);        // inverse-swizzled source col
  const int rsw = lo & 7;                            // read-side row&7

  auto stage = [&](int k0, int buf) {
#pragma unroll
    for (int i = 0; i < PER; ++i) {
      const int blk = wave * PER + i;
      if (blk < ACH) {
        const int row = blk * 8 + srow;
        gload16(A + (m0 + row) * (size_t)lda + k0 + scol, &As[buf][blk * 512]);
      } else {
        const int j = blk - ACH;
        const int row = j * 8 + srow;
        gload16(B + (n0 + row) * (size_t)ldb + k0 + scol, &Bs[buf][j * 512]);
      }
    }
  };

  f32x4 acc[4][NFR] = {};
  stage(0, 0);
  int cur = 0;
  for (int k0 = 0; k0 < Keff; k0 += 64) {
    __syncthreads();
    if (k0 + 64 < Keff) stage(k0 + 64, cur ^ 1);
#pragma unroll
    for (int kk = 0; kk < 2; ++kk) {
      const int ch = (((kk << 2) + hi) ^ rsw) << 3;
      bf16x8 af[4], bfr[NFR];
#pragma unroll
      for (int m = 0; m < 4; ++m)
        af[m] = *(const bf16x8*)&As[cur][(rowbase + m * 16 + lo) * 64 + ch];
#pragma unroll
      for (int n = 0; n < NFR; ++n)
        bfr[n] = *(const bf16x8*)&Bs[cur][(colbase + n * 16 + lo) * 64 + ch];
#pragma unroll
      for (int m = 0; m < 4; ++m)
#pragma unroll
        for (int n = 0; n < NFR; ++n)
          acc[m][n] = __builtin_amdgcn_mfma_f32_16x16x32_bf16(af[m], bfr[n], acc[m][n], 0, 0, 0);
    }
    cur ^= 1;
  }
  float* Cf = (float*)Cv;
  bf16* Cb = (bf16*)Cv;
  const size_t cbase = (size_t)bz * (size_t)bC;
#pragma unroll
  for (int m = 0; m < 4; ++m) {
    const size_t row = m0 + rowbase + m * 16 + hi * 4;
#pragma unroll
    for (int n = 0; n < NFR; ++n) {
      const int col = (int)n0 + colbase + n * 16 + lo;
      if (col < Nreal) {
        const float bv = BIAS ? bias[col] : 0.0f;
#pragma unroll
        for (int j = 0; j < 4; ++j) {
          const float v = acc[m][n][j] + bv;
          const size_t off = cbase + (row + j) * (size_t)ldc + col;
          if (BF16OUT) Cb[off] = __float2bfloat16(v);
          else         Cf[off] = v;
        }
      }
    }
  }
}

// ---------------------------------------------------------------------------
extern "C" void kernel_launch(void* const* d_in, const int* in_sizes, int n_in,
                              void* d_out, int out_size, void* d_ws, size_t ws_size,
                              hipStream_t stream) {
  const float* x       = (const float*)d_in[0];
  const float* wq_a_w  = (const float*)d_in[1];
  const float* wq_a_b  = (const float*)d_in[2];
  const float* q_norm  = (const float*)d_in[3];
  const float* wq_b_w  = (const float*)d_in[4];
  const float* wq_b_b  = (const float*)d_in[5];
  const float* wkv_a_w = (const float*)d_in[6];
  const float* wkv_a_b = (const float*)d_in[7];
  const float* kv_norm = (const float*)d_in[8];
  const float* wkv_b_w = (const float*)d_in[9];
  const float* wo_w    = (const float*)d_in[10];
  const float* wo_bias = (const float*)d_in[11];
  float* out = (float*)d_out;

  char* base = (char*)d_ws;
  // Transient staging region (all dead before attention):
  bf16*  xb   = (bf16*)(base + 0);          //  8,388,608
  bf16*  wqa  = (bf16*)(base + 8388608);    //  6,291,456
  bf16*  wqb  = (bf16*)(base + 14680064);   //  9,437,184
  bf16*  wkva = (bf16*)(base + 24117248);   //  2,621,440
  bf16*  wkvb = (bf16*)(base + 26738688);   //  4,194,304
  bf16*  qa   = (bf16*)(base + 30932992);   //  6,291,456
  bf16*  qn   = (bf16*)(base + 37224448);   //  6,291,456
  float* kvf  = (float*)(base + 43515904);  //  5,242,880
  bf16*  kvn  = (bf16*)(base + 48758784);   //  2,097,152
  // Persistent buffers:
  char* q = base + 134217728;
  bf16* qv   = (bf16*)(q);             q += 12582912;  // 2048x3072
  bf16* Kh   = (bf16*)(q);             q += 12582912;  // 16x2048x192
  bf16* V2T  = (bf16*)(q);             q += 8388608;   // 16x128x2048
  bf16* wob  = (bf16*)(q);             q += 8388608;   // 2048x2048
  bf16* oabs = (bf16*)(q);             q += 8388608;   // 2048x2048

  // all fp32->bf16 converts in one launch
  cvt_all<<<dim3(2048), 256, 0, stream>>>(x, wq_a_w, wq_b_w, wkv_a_w, wkv_b_w, wo_w,
                                          xb, wqa, wqb, wkva, wkvb, wob);

  // q_a = rmsnorm(x @ wq_a^T + b)
  gemm_bt<true, true, 64><<<dim3(12, 32, 1), 256, 0, stream>>>(
      xb, wqa, wq_a_b, qa, 2048, 2048, 1536, 2048, 1536, 0, 0, 0, 0);
  rmsnorm_bf16<<<2048, 256, 0, stream>>>(qa, q_norm, qn, 1536);
  // q = qn @ wq_b^T + b -> qv [2048][3072] (16 heads x 192)
  gemm_bt<true, true, 128><<<dim3(24, 16, 1), 256, 0, stream>>>(
      qn, wqb, wq_b_b, qv, 1536, 1536, 3072, 1536, 3072, 0, 0, 0, 0);
  q_rope<<<2048, 256, 0, stream>>>(qv);
  // kv_full = x @ wkv_a^T + b -> fp32 [2048][640] (576 valid)
  gemm_bt<true, false, 64><<<dim3(5, 32, 1), 256, 0, stream>>>(
      xb, wkva, wkv_a_b, kvf, 2048, 2048, 640, 2048, 576, 0, 0, 0, 0);
  kv_post<<<2048, 256, 0, stream>>>(kvf, kv_norm, kvn, Kh);
  // K_h nope: Kh[h][t][0..128) = kvn[t] . wkvb[h*256+d][:]  (d<128)
  gemm_bt<false, true, 64><<<dim3(1, 32, 16), 256, 0, stream>>>(
      kvn, wkvb, nullptr, Kh, 512, 512, 192, 512, 128,
      0, 256ll * 512, 2048ll * 192, 0);
  // V2T[h][d][t] = wkvb[h*256+128+d][:] . kvn[t][:]
  gemm_bt<false, true, 64><<<dim3(16, 2, 16), 256, 0, stream>>>(
      wkvb + 128ull * 512, kvn, nullptr, V2T, 512, 512, 2048, 512, 2048,
      256ll * 512, 0, 128ll * 2048, 0);

  // ---- fused flash attention -> oabs[q][h*128+d]
  attn_flash<<<dim3(32, 16), 256, 0, stream>>>(qv, Kh, V2T, oabs);

  // final: out = oabs @ wo^T + b (fp32 out)
  gemm_bt<true, false, 64><<<dim3(16, 32, 1), 256, 0, stream>>>(
      oabs, wob, wo_bias, out, 2048, 2048, 2048, 2048, 2048, 0, 0, 0, 0);
}

// Round 21
// 241.669 us; speedup vs baseline: 1.1144x; 1.1144x over previous
//
#include <hip/hip_runtime.h>
#include <hip/hip_bf16.h>
#include <stdint.h>

// MLA forward, bf16 MFMA pipeline. Prefill-optimal DECOMPRESSED attention:
// K_h = [kvn @ wkvb_nope^T | rope(k_pe)] (192-dim), V2T_h = wkvb_v @ kvn^T.
// Attention: fused flash kernel, KVBLK=64, Kn/Vt dbuf XOR-swizzled in LDS,
// rope K direct from global (L2), defer-rescale online softmax, head-parity
// qb pairing (33 tiles per CU), stage(t+1) issued first after the barrier.
// Shapes: B=1 S=2048 HID=2048 H=16 QLR=1536 KVLR=512 NOPE=128 ROPE=64 VD=128 QKD=192.

using bf16 = __hip_bfloat16;
typedef __bf16 bf16x8 __attribute__((ext_vector_type(8)));
typedef __bf16 bf16x4 __attribute__((ext_vector_type(4)));
typedef float f32x4 __attribute__((ext_vector_type(4)));

#define S_LEN 2048
#define NHEAD 16

static __device__ __forceinline__ void gload16(const void* g, void* l) {
  __builtin_amdgcn_global_load_lds(
      (const __attribute__((address_space(1))) unsigned int*)g,
      (__attribute__((address_space(3))) unsigned int*)l, 16, 0, 0);
}

// ---------------- fused fp32 -> bf16 converts (all 6 tensors, 1 launch) -----
__global__ void cvt_all(const float* __restrict__ x, const float* __restrict__ wqa_s,
                        const float* __restrict__ wqb_s, const float* __restrict__ wkva_s,
                        const float* __restrict__ wkvb_s, const float* __restrict__ wo_s,
                        bf16* __restrict__ xb, bf16* __restrict__ wqa,
                        bf16* __restrict__ wqb, bf16* __restrict__ wkva,
                        bf16* __restrict__ wkvb, bf16* __restrict__ wob) {
  // segment sizes in float4 units
  const size_t n0 = 1048576;           // x     2048x2048
  const size_t n1 = n0 + 786432;       // wq_a  1536x2048
  const size_t n2 = n1 + 1179648;      // wq_b  3072x1536
  const size_t n3 = n2 + 327680;       // wkv_a 576x2048 padded to 640 rows
  const size_t n4 = n3 + 524288;       // wkv_b 4096x512
  const size_t n5 = n4 + 1048576;      // wo    2048x2048
  auto cvt4 = [](const float4 v, bf16* d) {
    bf16x4 o;
    o[0] = (__bf16)__float2bfloat16(v.x);
    o[1] = (__bf16)__float2bfloat16(v.y);
    o[2] = (__bf16)__float2bfloat16(v.z);
    o[3] = (__bf16)__float2bfloat16(v.w);
    *(bf16x4*)d = o;
  };
  for (size_t i = (size_t)blockIdx.x * blockDim.x + threadIdx.x; i < n5;
       i += (size_t)gridDim.x * blockDim.x) {
    if (i < n0) {
      cvt4(*(const float4*)(x + i * 4), xb + i * 4);
    } else if (i < n1) {
      size_t j = i - n0;
      cvt4(*(const float4*)(wqa_s + j * 4), wqa + j * 4);
    } else if (i < n2) {
      size_t j = i - n1;
      cvt4(*(const float4*)(wqb_s + j * 4), wqb + j * 4);
    } else if (i < n3) {
      size_t j = i - n2;
      size_t e = j * 4;
      int r = (int)(e / 2048), c = (int)(e % 2048);
      float4 v = (r < 576) ? *(const float4*)(wkva_s + (size_t)r * 2048 + c)
                           : make_float4(0.f, 0.f, 0.f, 0.f);
      cvt4(v, wkva + e);
    } else if (i < n4) {
      size_t j = i - n3;
      cvt4(*(const float4*)(wkvb_s + j * 4), wkvb + j * 4);
    } else {
      size_t j = i - n4;
      cvt4(*(const float4*)(wo_s + j * 4), wob + j * 4);
    }
  }
}

// ---------------- row RMSNorm (bf16 in -> bf16 out) -------------------------
__global__ void rmsnorm_bf16(const bf16* __restrict__ in, const float* __restrict__ w,
                             bf16* __restrict__ out, int cols) {
  const int r = blockIdx.x, tid = threadIdx.x;
  const bf16* row = in + (size_t)r * cols;
  float ss = 0.f;
  for (int c = tid; c < cols; c += 256) {
    float v = __bfloat162float(row[c]);
    ss += v * v;
  }
  for (int m = 32; m >= 1; m >>= 1) ss += __shfl_xor(ss, m, 64);
  __shared__ float red[4];
  if ((tid & 63) == 0) red[tid >> 6] = ss;
  __syncthreads();
  ss = red[0] + red[1] + red[2] + red[3];
  float inv = rsqrtf(ss / (float)cols + 1e-6f);
  for (int c = tid; c < cols; c += 256)
    out[(size_t)r * cols + c] = __float2bfloat16(__bfloat162float(row[c]) * inv * w[c]);
}

// ---- kv post: rmsnorm(kv) -> kvn[t][512]; rope(k_pe) -> Kh[h][t][128..192) --
__global__ void kv_post(const float* __restrict__ kvf, const float* __restrict__ kvw,
                        bf16* __restrict__ kvn, bf16* __restrict__ Kh) {
  const int t = blockIdx.x, tid = threadIdx.x;
  const float* row = kvf + (size_t)t * 640;
  float ss = 0.f;
  for (int c = tid; c < 512; c += 256) { float v = row[c]; ss += v * v; }
  for (int m = 32; m >= 1; m >>= 1) ss += __shfl_xor(ss, m, 64);
  __shared__ float red[4];
  if ((tid & 63) == 0) red[tid >> 6] = ss;
  __syncthreads();
  ss = red[0] + red[1] + red[2] + red[3];
  float inv = rsqrtf(ss * (1.0f / 512.0f) + 1e-6f);
  for (int c = tid; c < 512; c += 256)
    kvn[(size_t)t * 512 + c] = __float2bfloat16(row[c] * inv * kvw[c]);
  if (tid < 32) {
    const int j = tid;
    float freq = expf(-(float)j * (1.0f / 32.0f) * 9.210340371976184f); // ln(10000)
    float ang = (float)t * freq;
    float cs = cosf(ang), sn = sinf(ang);
    float x1 = row[512 + j];
    float x2 = row[512 + j + 32];
    bf16 o1 = __float2bfloat16(x1 * cs - x2 * sn);
    bf16 o2 = __float2bfloat16(x2 * cs + x1 * sn);
#pragma unroll
    for (int h = 0; h < 16; ++h) {
      bf16* kr = Kh + ((size_t)h * S_LEN + t) * 192 + 128;
      kr[j] = o1;
      kr[j + 32] = o2;
    }
  }
}

// ---------------- q rope, in-place on qv[s][h*192+128 .. +192) --------------
__global__ void q_rope(bf16* __restrict__ qv) {
  const int s = blockIdx.x, tid = threadIdx.x;
  for (int it = tid; it < 512; it += 256) {
    const int h = it >> 5, j = it & 31;
    float freq = expf(-(float)j * (1.0f / 32.0f) * 9.210340371976184f);
    float ang = (float)s * freq;
    float cs = cosf(ang), sn = sinf(ang);
    bf16* base = qv + (size_t)s * 3072 + h * 192 + 128;
    float x1 = __bfloat162float(base[j]);
    float x2 = __bfloat162float(base[j + 32]);
    base[j] = __float2bfloat16(x1 * cs - x2 * sn);
    base[j + 32] = __float2bfloat16(x2 * cs + x1 * sn);
  }
}

// ---------------- fused flash attention (decompressed heads) ----------------
// grid (32 qb, 16 h) swizzled 8-XCD; 256 thr = 4 waves; wave w owns q rows
// qb*64+w*16..+16. KVBLK=64. LDS: Kn[2][64x128] + Vt[2][128x64] (both XOR-
// swizzled, dbuf) + Pl[4][16x72] = 73KB -> 2 blocks/CU. Rope K direct from
// global (L2-resident). Single barrier/tile; stage(t+1) issued FIRST after
// the barrier so staging has the whole tile to land. Head-parity qb pairing
// gives every CU exactly 33 tiles.
__global__ __launch_bounds__(256, 2)
void attn_flash(const bf16* __restrict__ qv, const bf16* __restrict__ Kh,
                const bf16* __restrict__ V2T, bf16* __restrict__ oabs) {
  const int lin = (int)blockIdx.x + 32 * (int)blockIdx.y;
  const int l2 = (lin & 7) * 64 + (lin >> 3);   // 512 blocks, 64 per XCD
  const int h = l2 >> 5;
  const int idx = l2 & 31;
  const int qb = (h & 1) ? idx : 31 - idx;      // heavy+light pairing per CU
  const int tid = threadIdx.x, w = tid >> 6, lane = tid & 63;
  const int lo = lane & 15, hi = lane >> 4;
  __shared__ bf16 Kn[2][64 * 128];   // 32 KB
  __shared__ bf16 Vt[2][128 * 64];   // 32 KB
  __shared__ bf16 Pl[4][16 * 72];    //  9 KB
  const int q0 = qb * 64 + w * 16;
  const int q = q0 + lo;

  // persistent Q fragments (lane lo = q col, hi*8 = k offset)
  bf16x8 Qf[6];
  {
    const bf16* qp = qv + (size_t)(q0 + lo) * 3072 + h * 192 + hi * 8;
#pragma unroll
    for (int ks = 0; ks < 6; ++ks) Qf[ks] = *(const bf16x8*)(qp + ks * 32);
  }
  f32x4 o[8];
#pragma unroll
  for (int cg = 0; cg < 8; ++cg) o[cg] = (f32x4){0.f, 0.f, 0.f, 0.f};
  float mrow = -3e38f, lrow = 0.f;

  const bf16* khh = Kh + (size_t)h * S_LEN * 192;
  const bf16* vth = V2T + (size_t)h * 128 * S_LEN;

  // stage tile tt (64 kv rows) into buffer b. Linear LDS dest (gload16);
  // inverse-XOR-swizzled global source chunks; read side applies same XOR.
  auto stage = [&](int tt, int b) {
    const int t0s = tt * 64;
#pragma unroll
    for (int i = 0; i < 4; ++i) {            // Kn: 16 calls (4/wave), 4 rows each
      const int c = w * 4 + i;
      const int row = c * 4 + (lane >> 4);
      gload16(khh + (size_t)(t0s + row) * 192 + (((lane & 15) ^ (row & 7)) << 3),
              &Kn[b][c * 512]);
    }
#pragma unroll
    for (int i = 0; i < 4; ++i) {            // Vt: 16 calls (4/wave), 8 rows each
      const int c = w * 4 + i;
      const int row = c * 8 + (lane >> 3);
      gload16(vth + (size_t)row * S_LEN + t0s + (((lane & 7) ^ (row & 7)) << 3),
              &Vt[b][c * 512]);
    }
  };

  const int ntile = qb + 1;
  stage(0, 0);
  for (int t = 0; t < ntile; ++t) {
    __syncthreads();  // own gload16s drained; tile t visible to all
    const int b = t & 1;
    const int t0 = t * 64;

    // stage next tile FIRST: its loads get the whole tile body to land
    if (t + 1 < ntile) stage(t + 1, b ^ 1);

    // rope K fragments direct from global (used after nope QK)
    bf16x8 rk[2][4];
#pragma unroll
    for (int ks2 = 0; ks2 < 2; ++ks2)
#pragma unroll
      for (int f = 0; f < 4; ++f)
        rk[ks2][f] = *(const bf16x8*)(khh + (size_t)(t0 + f * 16 + lo) * 192 + 128 +
                                      ks2 * 32 + hi * 8);

    // ---- S^T = K · Q  (A = K rows t, B = Q cols q); nope from LDS, rope regs
    f32x4 sc[4];
#pragma unroll
    for (int f = 0; f < 4; ++f) sc[f] = (f32x4){0.f, 0.f, 0.f, 0.f};
#pragma unroll
    for (int ks = 0; ks < 4; ++ks)
#pragma unroll
      for (int f = 0; f < 4; ++f) {
        const int row = f * 16 + lo;
        bf16x8 kf = *(const bf16x8*)&Kn[b][row * 128 + ((((ks << 2) + hi) ^ (row & 7)) << 3)];
        sc[f] = __builtin_amdgcn_mfma_f32_16x16x32_bf16(kf, Qf[ks], sc[f], 0, 0, 0);
      }
#pragma unroll
    for (int ks2 = 0; ks2 < 2; ++ks2)
#pragma unroll
      for (int f = 0; f < 4; ++f)
        sc[f] = __builtin_amdgcn_mfma_f32_16x16x32_bf16(rk[ks2][f], Qf[4 + ks2], sc[f], 0, 0, 0);

    // ---- mask + scale + row max (lane-local row q = q0 + lo)
    const bool diag = (t == qb);
    float rmax = -3e38f;
#pragma unroll
    for (int f = 0; f < 4; ++f)
#pragma unroll
      for (int j = 0; j < 4; ++j) {
        float v = sc[f][j] * 0.0721687836487032f;  // 1/sqrt(192)
        if (diag && (t0 + f * 16 + hi * 4 + j > q)) v = -3e38f;
        sc[f][j] = v;
        rmax = fmaxf(rmax, v);
      }
    rmax = fmaxf(rmax, __shfl_xor(rmax, 16, 64));
    rmax = fmaxf(rmax, __shfl_xor(rmax, 32, 64));

    // ---- defer-rescale: only when the running max actually grows
    if (!__all(rmax <= mrow)) {
      const float mn = fmaxf(mrow, rmax);
      const float fsc = __expf(mrow - mn);
      mrow = mn;
      lrow *= fsc;
      float fscO[4];
#pragma unroll
      for (int j = 0; j < 4; ++j) fscO[j] = __shfl(fsc, hi * 4 + j, 64);
#pragma unroll
      for (int cg = 0; cg < 8; ++cg)
#pragma unroll
        for (int j = 0; j < 4; ++j) o[cg][j] *= fscO[j];
    }

    // ---- P = exp(v - mrow) -> Pl (bf16 pairs), rsum
    float rsum = 0.f;
    bf16* prow = &Pl[w][lo * 72];
#pragma unroll
    for (int f = 0; f < 4; ++f) {
      float pj[4];
#pragma unroll
      for (int j = 0; j < 4; ++j) {
        pj[j] = __expf(sc[f][j] - mrow);
        rsum += pj[j];
      }
#pragma unroll
      for (int i2 = 0; i2 < 2; ++i2) {
        uint32_t lo16 = (uint32_t)__bfloat16_as_ushort(__float2bfloat16(pj[i2 * 2]));
        uint32_t hi16 = (uint32_t)__bfloat16_as_ushort(__float2bfloat16(pj[i2 * 2 + 1]));
        *(uint32_t*)(prow + f * 16 + hi * 4 + i2 * 2) = lo16 | (hi16 << 16);
      }
    }
    rsum += __shfl_xor(rsum, 16, 64);
    rsum += __shfl_xor(rsum, 32, 64);
    lrow += rsum;

    // ---- PV: pa from own wave's Pl, V from swizzled Vt
#pragma unroll
    for (int tk = 0; tk < 2; ++tk) {
      bf16x8 pa = *(const bf16x8*)&Pl[w][lo * 72 + tk * 32 + hi * 8];
#pragma unroll
      for (int cg = 0; cg < 8; ++cg) {
        const int vrow = cg * 16 + lo;
        bf16x8 vf = *(const bf16x8*)&Vt[b][vrow * 64 + ((((tk << 2) + hi) ^ (vrow & 7)) << 3)];
        o[cg] = __builtin_amdgcn_mfma_f32_16x16x32_bf16(pa, vf, o[cg], 0, 0, 0);
      }
    }
  }

  // ---- epilogue: normalize by 1/lrow (per q row) and store
  const float linv = 1.0f / lrow;
  float linvO[4];
#pragma unroll
  for (int j = 0; j < 4; ++j) linvO[j] = __shfl(linv, hi * 4 + j, 64);
  bf16* ob = oabs + (size_t)q0 * 2048 + h * 128;
#pragma unroll
  for (int j = 0; j < 4; ++j)
#pragma unroll
    for (int cg = 0; cg < 8; ++cg)
      ob[(size_t)(hi * 4 + j) * 2048 + cg * 16 + lo] =
          __float2bfloat16(o[cg][j] * linvO[j]);
}

// ---------------- GEMM: C[m][n] = sum_k A[m][k]*B[n][k] (+bias[n]) ----------
// BM x 128 tile, 4 waves (256 thr) both variants.
//   BM=128: wave = 64x64 quadrant (acc[4][4]), 64KB LDS, 2 blocks/CU.
//   BM=64:  wave = 64x32 column stripe (acc[4][2]), 48KB LDS, 3 blocks/CU.
// BK=64, mfma 16x16x32, double-buffered LDS, prefetch-before-compute, ONE
// barrier per k-step. T2 XOR-swizzle on LDS. XCD-aware bijective swizzle.
template <bool BIAS, bool BF16OUT, int BM>
__global__ __launch_bounds__(256)
void gemm_bt(const bf16* __restrict__ A, const bf16* __restrict__ B,
             const float* __restrict__ bias, void* __restrict__ Cv,
             int lda, int ldb, int ldc, int K, int Nreal,
             long long bA, long long bB, long long bC, int mode) {
  // XCD swizzle: contiguous tile-chunk per XCD
  int bx, byi, bz;
  {
    const int gx = gridDim.x, gy = gridDim.y;
    const int nwg = gx * gy * (int)gridDim.z;
    const int lin = (int)blockIdx.x + gx * ((int)blockIdx.y + gy * (int)blockIdx.z);
    const int cpx = nwg >> 3;
    const int l2 = (lin & 7) * cpx + (lin >> 3);
    bx = l2 % gx;
    byi = (l2 / gx) % gy;
    bz = l2 / (gx * gy);
    if (mode) byi = (bz & 1) ? byi : gy - 1 - byi;
  }
  const size_t m0 = (size_t)byi * BM, n0 = (size_t)bx * 128;
  if (mode == 1 && (int)n0 >= (int)m0 + BM) return;
  const int Keff = (mode == 2) ? ((K < (int)m0 + BM) ? K : (int)m0 + BM) : K;

  constexpr int ACH = BM / 8;                  // A 1KB chunks
  constexpr int PER = (ACH + 16) / 4;          // chunks per wave (6 or 8)
  constexpr int NFR = (BM == 64) ? 2 : 4;      // n fragments per wave
  __shared__ bf16 As[2][BM * 64];
  __shared__ bf16 Bs[2][8192];
  const int tid = threadIdx.x;
  const int wave = tid >> 6, lane = tid & 63;
  const int lo = lane & 15, hi = lane >> 4;
  const int rowbase = (BM == 64) ? 0 : ((wave >> 1) * 64);
  const int colbase = (BM == 64) ? (wave * 32) : ((wave & 1) * 64);
  A += (size_t)bz * (size_t)bA;
  B += (size_t)bz * (size_t)bB;
  const int srow = lane >> 3;                        // 0..7 (also row&7)
  const int scol = (((lane & 7) ^ srow) * 8);        // inverse-swizzled source col
  const int rsw = lo & 7;                            // read-side row&7

  auto stage = [&](int k0, int buf) {
#pragma unroll
    for (int i = 0; i < PER; ++i) {
      const int blk = wave * PER + i;
      if (blk < ACH) {
        const int row = blk * 8 + srow;
        gload16(A + (m0 + row) * (size_t)lda + k0 + scol, &As[buf][blk * 512]);
      } else {
        const int j = blk - ACH;
        const int row = j * 8 + srow;
        gload16(B + (n0 + row) * (size_t)ldb + k0 + scol, &Bs[buf][j * 512]);
      }
    }
  };

  f32x4 acc[4][NFR] = {};
  stage(0, 0);
  int cur = 0;
  for (int k0 = 0; k0 < Keff; k0 += 64) {
    __syncthreads();
    if (k0 + 64 < Keff) stage(k0 + 64, cur ^ 1);
#pragma unroll
    for (int kk = 0; kk < 2; ++kk) {
      const int ch = (((kk << 2) + hi) ^ rsw) << 3;
      bf16x8 af[4], bfr[NFR];
#pragma unroll
      for (int m = 0; m < 4; ++m)
        af[m] = *(const bf16x8*)&As[cur][(rowbase + m * 16 + lo) * 64 + ch];
#pragma unroll
      for (int n = 0; n < NFR; ++n)
        bfr[n] = *(const bf16x8*)&Bs[cur][(colbase + n * 16 + lo) * 64 + ch];
#pragma unroll
      for (int m = 0; m < 4; ++m)
#pragma unroll
        for (int n = 0; n < NFR; ++n)
          acc[m][n] = __builtin_amdgcn_mfma_f32_16x16x32_bf16(af[m], bfr[n], acc[m][n], 0, 0, 0);
    }
    cur ^= 1;
  }
  float* Cf = (float*)Cv;
  bf16* Cb = (bf16*)Cv;
  const size_t cbase = (size_t)bz * (size_t)bC;
#pragma unroll
  for (int m = 0; m < 4; ++m) {
    const size_t row = m0 + rowbase + m * 16 + hi * 4;
#pragma unroll
    for (int n = 0; n < NFR; ++n) {
      const int col = (int)n0 + colbase + n * 16 + lo;
      if (col < Nreal) {
        const float bv = BIAS ? bias[col] : 0.0f;
#pragma unroll
        for (int j = 0; j < 4; ++j) {
          const float v = acc[m][n][j] + bv;
          const size_t off = cbase + (row + j) * (size_t)ldc + col;
          if (BF16OUT) Cb[off] = __float2bfloat16(v);
          else         Cf[off] = v;
        }
      }
    }
  }
}

// ---------------------------------------------------------------------------
extern "C" void kernel_launch(void* const* d_in, const int* in_sizes, int n_in,
                              void* d_out, int out_size, void* d_ws, size_t ws_size,
                              hipStream_t stream) {
  const float* x       = (const float*)d_in[0];
  const float* wq_a_w  = (const float*)d_in[1];
  const float* wq_a_b  = (const float*)d_in[2];
  const float* q_norm  = (const float*)d_in[3];
  const float* wq_b_w  = (const float*)d_in[4];
  const float* wq_b_b  = (const float*)d_in[5];
  const float* wkv_a_w = (const float*)d_in[6];
  const float* wkv_a_b = (const float*)d_in[7];
  const float* kv_norm = (const float*)d_in[8];
  const float* wkv_b_w = (const float*)d_in[9];
  const float* wo_w    = (const float*)d_in[10];
  const float* wo_bias = (const float*)d_in[11];
  float* out = (float*)d_out;

  char* base = (char*)d_ws;
  // Transient staging region (all dead before attention):
  bf16*  xb   = (bf16*)(base + 0);          //  8,388,608
  bf16*  wqa  = (bf16*)(base + 8388608);    //  6,291,456
  bf16*  wqb  = (bf16*)(base + 14680064);   //  9,437,184
  bf16*  wkva = (bf16*)(base + 24117248);   //  2,621,440
  bf16*  wkvb = (bf16*)(base + 26738688);   //  4,194,304
  bf16*  qa   = (bf16*)(base + 30932992);   //  6,291,456
  bf16*  qn   = (bf16*)(base + 37224448);   //  6,291,456
  float* kvf  = (float*)(base + 43515904);  //  5,242,880
  bf16*  kvn  = (bf16*)(base + 48758784);   //  2,097,152
  // Persistent buffers:
  char* q = base + 134217728;
  bf16* qv   = (bf16*)(q);             q += 12582912;  // 2048x3072
  bf16* Kh   = (bf16*)(q);             q += 12582912;  // 16x2048x192
  bf16* V2T  = (bf16*)(q);             q += 8388608;   // 16x128x2048
  bf16* wob  = (bf16*)(q);             q += 8388608;   // 2048x2048
  bf16* oabs = (bf16*)(q);             q += 8388608;   // 2048x2048

  // all fp32->bf16 converts in one launch
  cvt_all<<<dim3(2048), 256, 0, stream>>>(x, wq_a_w, wq_b_w, wkv_a_w, wkv_b_w, wo_w,
                                          xb, wqa, wqb, wkva, wkvb, wob);

  // q_a = rmsnorm(x @ wq_a^T + b)
  gemm_bt<true, true, 64><<<dim3(12, 32, 1), 256, 0, stream>>>(
      xb, wqa, wq_a_b, qa, 2048, 2048, 1536, 2048, 1536, 0, 0, 0, 0);
  rmsnorm_bf16<<<2048, 256, 0, stream>>>(qa, q_norm, qn, 1536);
  // q = qn @ wq_b^T + b -> qv [2048][3072] (16 heads x 192)
  gemm_bt<true, true, 128><<<dim3(24, 16, 1), 256, 0, stream>>>(
      qn, wqb, wq_b_b, qv, 1536, 1536, 3072, 1536, 3072, 0, 0, 0, 0);
  q_rope<<<2048, 256, 0, stream>>>(qv);
  // kv_full = x @ wkv_a^T + b -> fp32 [2048][640] (576 valid)
  gemm_bt<true, false, 64><<<dim3(5, 32, 1), 256, 0, stream>>>(
      xb, wkva, wkv_a_b, kvf, 2048, 2048, 640, 2048, 576, 0, 0, 0, 0);
  kv_post<<<2048, 256, 0, stream>>>(kvf, kv_norm, kvn, Kh);
  // K_h nope: Kh[h][t][0..128) = kvn[t] . wkvb[h*256+d][:]  (d<128)
  gemm_bt<false, true, 64><<<dim3(1, 32, 16), 256, 0, stream>>>(
      kvn, wkvb, nullptr, Kh, 512, 512, 192, 512, 128,
      0, 256ll * 512, 2048ll * 192, 0);
  // V2T[h][d][t] = wkvb[h*256+128+d][:] . kvn[t][:]
  gemm_bt<false, true, 64><<<dim3(16, 2, 16), 256, 0, stream>>>(
      wkvb + 128ull * 512, kvn, nullptr, V2T, 512, 512, 2048, 512, 2048,
      256ll * 512, 0, 128ll * 2048, 0);

  // ---- fused flash attention -> oabs[q][h*128+d]
  attn_flash<<<dim3(32, 16), 256, 0, stream>>>(qv, Kh, V2T, oabs);

  // final: out = oabs @ wo^T + b (fp32 out)
  gemm_bt<true, false, 64><<<dim3(16, 32, 1), 256, 0, stream>>>(
      oabs, wob, wo_bias, out, 2048, 2048, 2048, 2048, 2048, 0, 0, 0, 0);
}

// Round 22
// 224.278 us; speedup vs baseline: 1.2008x; 1.0775x over previous
//
#include <hip/hip_runtime.h>
#include <hip/hip_bf16.h>
#include <stdint.h>

// MLA forward, bf16 MFMA pipeline. Prefill-optimal DECOMPRESSED attention:
// K_h = [kvn @ wkvb_nope^T | rope(k_pe)] (192-dim), V2T_h = wkvb_v @ kvn^T.
// Attention: split-K fused flash (flash-decoding): 1024 uniform jobs
// (each <=16 KV tiles, heavy-first) writing unnormalized (o,m,l) partials,
// then a combine kernel. KVBLK=64, Kn/Vt dbuf XOR-swizzled LDS, rope K from
// global (L2), defer-rescale online softmax.
// Shapes: B=1 S=2048 HID=2048 H=16 QLR=1536 KVLR=512 NOPE=128 ROPE=64 VD=128 QKD=192.

using bf16 = __hip_bfloat16;
typedef __bf16 bf16x8 __attribute__((ext_vector_type(8)));
typedef __bf16 bf16x4 __attribute__((ext_vector_type(4)));
typedef float f32x4 __attribute__((ext_vector_type(4)));

#define S_LEN 2048
#define NHEAD 16

static __device__ __forceinline__ void gload16(const void* g, void* l) {
  __builtin_amdgcn_global_load_lds(
      (const __attribute__((address_space(1))) unsigned int*)g,
      (__attribute__((address_space(3))) unsigned int*)l, 16, 0, 0);
}

// ---------------- fused fp32 -> bf16 converts (all 6 tensors, 1 launch) -----
__global__ void cvt_all(const float* __restrict__ x, const float* __restrict__ wqa_s,
                        const float* __restrict__ wqb_s, const float* __restrict__ wkva_s,
                        const float* __restrict__ wkvb_s, const float* __restrict__ wo_s,
                        bf16* __restrict__ xb, bf16* __restrict__ wqa,
                        bf16* __restrict__ wqb, bf16* __restrict__ wkva,
                        bf16* __restrict__ wkvb, bf16* __restrict__ wob) {
  // segment sizes in float4 units
  const size_t n0 = 1048576;           // x     2048x2048
  const size_t n1 = n0 + 786432;       // wq_a  1536x2048
  const size_t n2 = n1 + 1179648;      // wq_b  3072x1536
  const size_t n3 = n2 + 327680;       // wkv_a 576x2048 padded to 640 rows
  const size_t n4 = n3 + 524288;       // wkv_b 4096x512
  const size_t n5 = n4 + 1048576;      // wo    2048x2048
  auto cvt4 = [](const float4 v, bf16* d) {
    bf16x4 o;
    o[0] = (__bf16)__float2bfloat16(v.x);
    o[1] = (__bf16)__float2bfloat16(v.y);
    o[2] = (__bf16)__float2bfloat16(v.z);
    o[3] = (__bf16)__float2bfloat16(v.w);
    *(bf16x4*)d = o;
  };
  for (size_t i = (size_t)blockIdx.x * blockDim.x + threadIdx.x; i < n5;
       i += (size_t)gridDim.x * blockDim.x) {
    if (i < n0) {
      cvt4(*(const float4*)(x + i * 4), xb + i * 4);
    } else if (i < n1) {
      size_t j = i - n0;
      cvt4(*(const float4*)(wqa_s + j * 4), wqa + j * 4);
    } else if (i < n2) {
      size_t j = i - n1;
      cvt4(*(const float4*)(wqb_s + j * 4), wqb + j * 4);
    } else if (i < n3) {
      size_t j = i - n2;
      size_t e = j * 4;
      int r = (int)(e / 2048), c = (int)(e % 2048);
      float4 v = (r < 576) ? *(const float4*)(wkva_s + (size_t)r * 2048 + c)
                           : make_float4(0.f, 0.f, 0.f, 0.f);
      cvt4(v, wkva + e);
    } else if (i < n4) {
      size_t j = i - n3;
      cvt4(*(const float4*)(wkvb_s + j * 4), wkvb + j * 4);
    } else {
      size_t j = i - n4;
      cvt4(*(const float4*)(wo_s + j * 4), wob + j * 4);
    }
  }
}

// ---------------- row RMSNorm (bf16 in -> bf16 out) -------------------------
__global__ void rmsnorm_bf16(const bf16* __restrict__ in, const float* __restrict__ w,
                             bf16* __restrict__ out, int cols) {
  const int r = blockIdx.x, tid = threadIdx.x;
  const bf16* row = in + (size_t)r * cols;
  float ss = 0.f;
  for (int c = tid; c < cols; c += 256) {
    float v = __bfloat162float(row[c]);
    ss += v * v;
  }
  for (int m = 32; m >= 1; m >>= 1) ss += __shfl_xor(ss, m, 64);
  __shared__ float red[4];
  if ((tid & 63) == 0) red[tid >> 6] = ss;
  __syncthreads();
  ss = red[0] + red[1] + red[2] + red[3];
  float inv = rsqrtf(ss / (float)cols + 1e-6f);
  for (int c = tid; c < cols; c += 256)
    out[(size_t)r * cols + c] = __float2bfloat16(__bfloat162float(row[c]) * inv * w[c]);
}

// ---- kv post: rmsnorm(kv) -> kvn[t][512]; rope(k_pe) -> Kh[h][t][128..192) --
__global__ void kv_post(const float* __restrict__ kvf, const float* __restrict__ kvw,
                        bf16* __restrict__ kvn, bf16* __restrict__ Kh) {
  const int t = blockIdx.x, tid = threadIdx.x;
  const float* row = kvf + (size_t)t * 640;
  float ss = 0.f;
  for (int c = tid; c < 512; c += 256) { float v = row[c]; ss += v * v; }
  for (int m = 32; m >= 1; m >>= 1) ss += __shfl_xor(ss, m, 64);
  __shared__ float red[4];
  if ((tid & 63) == 0) red[tid >> 6] = ss;
  __syncthreads();
  ss = red[0] + red[1] + red[2] + red[3];
  float inv = rsqrtf(ss * (1.0f / 512.0f) + 1e-6f);
  for (int c = tid; c < 512; c += 256)
    kvn[(size_t)t * 512 + c] = __float2bfloat16(row[c] * inv * kvw[c]);
  if (tid < 32) {
    const int j = tid;
    float freq = expf(-(float)j * (1.0f / 32.0f) * 9.210340371976184f); // ln(10000)
    float ang = (float)t * freq;
    float cs = cosf(ang), sn = sinf(ang);
    float x1 = row[512 + j];
    float x2 = row[512 + j + 32];
    bf16 o1 = __float2bfloat16(x1 * cs - x2 * sn);
    bf16 o2 = __float2bfloat16(x2 * cs + x1 * sn);
#pragma unroll
    for (int h = 0; h < 16; ++h) {
      bf16* kr = Kh + ((size_t)h * S_LEN + t) * 192 + 128;
      kr[j] = o1;
      kr[j + 32] = o2;
    }
  }
}

// ---------------- q rope, in-place on qv[s][h*192+128 .. +192) --------------
__global__ void q_rope(bf16* __restrict__ qv) {
  const int s = blockIdx.x, tid = threadIdx.x;
  for (int it = tid; it < 512; it += 256) {
    const int h = it >> 5, j = it & 31;
    float freq = expf(-(float)j * (1.0f / 32.0f) * 9.210340371976184f);
    float ang = (float)s * freq;
    float cs = cosf(ang), sn = sinf(ang);
    bf16* base = qv + (size_t)s * 3072 + h * 192 + 128;
    float x1 = __bfloat162float(base[j]);
    float x2 = __bfloat162float(base[j + 32]);
    base[j] = __float2bfloat16(x1 * cs - x2 * sn);
    base[j + 32] = __float2bfloat16(x2 * cs + x1 * sn);
  }
}

// ---------------- split-K fused flash attention -----------------------------
// 1024 jobs: j -> h = j&15, split s = (j>>4)&1, qb = 31-(j>>5) (heavy first).
// Job processes KV tiles [s? nt/2 : 0, s? nt : nt/2), nt = qb+1 (<=16 tiles).
// 256 thr = 4 waves; wave w owns q rows qb*64+w*16..+16. KVBLK=64.
// LDS: Kn[2][64x128] + Vt[2][128x64] (XOR-swizzled dbuf) + Pl[4][16x72] = 73KB.
// Writes UNNORMALIZED o (fp32) + per-row m,l partials for the combine kernel.
__global__ __launch_bounds__(256, 2)
void attn_split(const bf16* __restrict__ qv, const bf16* __restrict__ Kh,
                const bf16* __restrict__ V2T, float* __restrict__ oP,
                float* __restrict__ mP, float* __restrict__ lP) {
  const int jb = (int)blockIdx.x;
  const int h = jb & 15;
  const int sp = (jb >> 4) & 1;
  const int qb = 31 - (jb >> 5);
  const int tid = threadIdx.x, w = tid >> 6, lane = tid & 63;
  const int lo = lane & 15, hi = lane >> 4;
  __shared__ bf16 Kn[2][64 * 128];   // 32 KB
  __shared__ bf16 Vt[2][128 * 64];   // 32 KB
  __shared__ bf16 Pl[4][16 * 72];    //  9 KB
  const int q0 = qb * 64 + w * 16;
  const int q = q0 + lo;

  // persistent Q fragments (lane lo = q col, hi*8 = k offset)
  bf16x8 Qf[6];
  {
    const bf16* qp = qv + (size_t)(q0 + lo) * 3072 + h * 192 + hi * 8;
#pragma unroll
    for (int ks = 0; ks < 6; ++ks) Qf[ks] = *(const bf16x8*)(qp + ks * 32);
  }
  f32x4 o[8];
#pragma unroll
  for (int cg = 0; cg < 8; ++cg) o[cg] = (f32x4){0.f, 0.f, 0.f, 0.f};
  float mrow = -3e38f, lrow = 0.f;

  const bf16* khh = Kh + (size_t)h * S_LEN * 192;
  const bf16* vth = V2T + (size_t)h * 128 * S_LEN;

  auto stage = [&](int tt, int b) {
    const int t0s = tt * 64;
#pragma unroll
    for (int i = 0; i < 4; ++i) {            // Kn: 16 calls (4/wave), 4 rows each
      const int c = w * 4 + i;
      const int row = c * 4 + (lane >> 4);
      gload16(khh + (size_t)(t0s + row) * 192 + (((lane & 15) ^ (row & 7)) << 3),
              &Kn[b][c * 512]);
    }
#pragma unroll
    for (int i = 0; i < 4; ++i) {            // Vt: 16 calls (4/wave), 8 rows each
      const int c = w * 4 + i;
      const int row = c * 8 + (lane >> 3);
      gload16(vth + (size_t)row * S_LEN + t0s + (((lane & 7) ^ (row & 7)) << 3),
              &Vt[b][c * 512]);
    }
  };

  const int nt = qb + 1;
  const int tb = sp ? (nt >> 1) : 0;
  const int te = sp ? nt : (nt >> 1);
  if (tb < te) stage(tb, tb & 1);
  for (int t = tb; t < te; ++t) {
    __syncthreads();  // own gload16s drained; tile t visible to all
    const int b = t & 1;
    const int t0 = t * 64;

    if (t + 1 < te) stage(t + 1, b ^ 1);

    // rope K fragments direct from global (used after nope QK)
    bf16x8 rk[2][4];
#pragma unroll
    for (int ks2 = 0; ks2 < 2; ++ks2)
#pragma unroll
      for (int f = 0; f < 4; ++f)
        rk[ks2][f] = *(const bf16x8*)(khh + (size_t)(t0 + f * 16 + lo) * 192 + 128 +
                                      ks2 * 32 + hi * 8);

    // ---- S^T = K · Q  (A = K rows t, B = Q cols q); nope from LDS, rope regs
    f32x4 sc[4];
#pragma unroll
    for (int f = 0; f < 4; ++f) sc[f] = (f32x4){0.f, 0.f, 0.f, 0.f};
#pragma unroll
    for (int ks = 0; ks < 4; ++ks)
#pragma unroll
      for (int f = 0; f < 4; ++f) {
        const int row = f * 16 + lo;
        bf16x8 kf = *(const bf16x8*)&Kn[b][row * 128 + ((((ks << 2) + hi) ^ (row & 7)) << 3)];
        sc[f] = __builtin_amdgcn_mfma_f32_16x16x32_bf16(kf, Qf[ks], sc[f], 0, 0, 0);
      }
#pragma unroll
    for (int ks2 = 0; ks2 < 2; ++ks2)
#pragma unroll
      for (int f = 0; f < 4; ++f)
        sc[f] = __builtin_amdgcn_mfma_f32_16x16x32_bf16(rk[ks2][f], Qf[4 + ks2], sc[f], 0, 0, 0);

    // ---- mask + scale + row max (lane-local row q = q0 + lo)
    const bool diag = (t == qb);
    float rmax = -3e38f;
#pragma unroll
    for (int f = 0; f < 4; ++f)
#pragma unroll
      for (int j = 0; j < 4; ++j) {
        float v = sc[f][j] * 0.0721687836487032f;  // 1/sqrt(192)
        if (diag && (t0 + f * 16 + hi * 4 + j > q)) v = -3e38f;
        sc[f][j] = v;
        rmax = fmaxf(rmax, v);
      }
    rmax = fmaxf(rmax, __shfl_xor(rmax, 16, 64));
    rmax = fmaxf(rmax, __shfl_xor(rmax, 32, 64));

    // ---- defer-rescale: only when the running max actually grows
    if (!__all(rmax <= mrow)) {
      const float mn = fmaxf(mrow, rmax);
      const float fsc = __expf(mrow - mn);
      mrow = mn;
      lrow *= fsc;
      float fscO[4];
#pragma unroll
      for (int j = 0; j < 4; ++j) fscO[j] = __shfl(fsc, hi * 4 + j, 64);
#pragma unroll
      for (int cg = 0; cg < 8; ++cg)
#pragma unroll
        for (int j = 0; j < 4; ++j) o[cg][j] *= fscO[j];
    }

    // ---- P = exp(v - mrow) -> Pl (bf16 pairs), rsum
    float rsum = 0.f;
    bf16* prow = &Pl[w][lo * 72];
#pragma unroll
    for (int f = 0; f < 4; ++f) {
      float pj[4];
#pragma unroll
      for (int j = 0; j < 4; ++j) {
        pj[j] = __expf(sc[f][j] - mrow);
        rsum += pj[j];
      }
#pragma unroll
      for (int i2 = 0; i2 < 2; ++i2) {
        uint32_t lo16 = (uint32_t)__bfloat16_as_ushort(__float2bfloat16(pj[i2 * 2]));
        uint32_t hi16 = (uint32_t)__bfloat16_as_ushort(__float2bfloat16(pj[i2 * 2 + 1]));
        *(uint32_t*)(prow + f * 16 + hi * 4 + i2 * 2) = lo16 | (hi16 << 16);
      }
    }
    rsum += __shfl_xor(rsum, 16, 64);
    rsum += __shfl_xor(rsum, 32, 64);
    lrow += rsum;

    // ---- PV: pa from own wave's Pl, V from swizzled Vt
#pragma unroll
    for (int tk = 0; tk < 2; ++tk) {
      bf16x8 pa = *(const bf16x8*)&Pl[w][lo * 72 + tk * 32 + hi * 8];
#pragma unroll
      for (int cg = 0; cg < 8; ++cg) {
        const int vrow = cg * 16 + lo;
        bf16x8 vf = *(const bf16x8*)&Vt[b][vrow * 64 + ((((tk << 2) + hi) ^ (vrow & 7)) << 3)];
        o[cg] = __builtin_amdgcn_mfma_f32_16x16x32_bf16(pa, vf, o[cg], 0, 0, 0);
      }
    }
  }

  // ---- epilogue: store raw partials (no normalize)
  float* op = oP + (((size_t)sp * 16 + h) * S_LEN + q0) * 128;
#pragma unroll
  for (int j = 0; j < 4; ++j)
#pragma unroll
    for (int cg = 0; cg < 8; ++cg)
      op[(size_t)(hi * 4 + j) * 128 + cg * 16 + lo] = o[cg][j];
  if (hi == 0) {
    const size_t mi = ((size_t)sp * 16 + h) * S_LEN + q0 + lo;
    mP[mi] = mrow;
    lP[mi] = lrow;
  }
}

// ---------------- combine: merge the 2 split partials -> oabs ---------------
// grid (1024, 16), 256 thr: 2 q rows x 128 cols per block.
__global__ void attn_combine(const float* __restrict__ oP, const float* __restrict__ mP,
                             const float* __restrict__ lP, bf16* __restrict__ oabs) {
  const int qq = (int)blockIdx.x * 2 + ((int)threadIdx.x >> 7);
  const int hh = (int)blockIdx.y;
  const int d = (int)threadIdx.x & 127;
  const size_t i0 = (size_t)hh * S_LEN + qq;
  const size_t i1 = (size_t)(16 + hh) * S_LEN + qq;
  const float m0 = mP[i0], m1 = mP[i1];
  const float l0 = lP[i0], l1 = lP[i1];
  const float M = fmaxf(m0, m1);
  const float w0 = __expf(m0 - M), w1 = __expf(m1 - M);
  const float li = 1.0f / (l0 * w0 + l1 * w1);
  const float v = (oP[i0 * 128 + d] * w0 + oP[i1 * 128 + d] * w1) * li;
  oabs[(size_t)qq * 2048 + hh * 128 + d] = __float2bfloat16(v);
}

// ---------------- GEMM: C[m][n] = sum_k A[m][k]*B[n][k] (+bias[n]) ----------
// BM x 128 tile, 4 waves (256 thr) both variants.
//   BM=128: wave = 64x64 quadrant (acc[4][4]), 64KB LDS, 2 blocks/CU.
//   BM=64:  wave = 64x32 column stripe (acc[4][2]), 48KB LDS, 3 blocks/CU.
// BK=64, mfma 16x16x32, double-buffered LDS, prefetch-before-compute, ONE
// barrier per k-step. T2 XOR-swizzle on LDS. XCD-aware bijective swizzle.
template <bool BIAS, bool BF16OUT, int BM>
__global__ __launch_bounds__(256)
void gemm_bt(const bf16* __restrict__ A, const bf16* __restrict__ B,
             const float* __restrict__ bias, void* __restrict__ Cv,
             int lda, int ldb, int ldc, int K, int Nreal,
             long long bA, long long bB, long long bC, int mode) {
  // XCD swizzle: contiguous tile-chunk per XCD
  int bx, byi, bz;
  {
    const int gx = gridDim.x, gy = gridDim.y;
    const int nwg = gx * gy * (int)gridDim.z;
    const int lin = (int)blockIdx.x + gx * ((int)blockIdx.y + gy * (int)blockIdx.z);
    const int cpx = nwg >> 3;
    const int l2 = (lin & 7) * cpx + (lin >> 3);
    bx = l2 % gx;
    byi = (l2 / gx) % gy;
    bz = l2 / (gx * gy);
    if (mode) byi = (bz & 1) ? byi : gy - 1 - byi;
  }
  const size_t m0 = (size_t)byi * BM, n0 = (size_t)bx * 128;
  if (mode == 1 && (int)n0 >= (int)m0 + BM) return;
  const int Keff = (mode == 2) ? ((K < (int)m0 + BM) ? K : (int)m0 + BM) : K;

  constexpr int ACH = BM / 8;                  // A 1KB chunks
  constexpr int PER = (ACH + 16) / 4;          // chunks per wave (6 or 8)
  constexpr int NFR = (BM == 64) ? 2 : 4;      // n fragments per wave
  __shared__ bf16 As[2][BM * 64];
  __shared__ bf16 Bs[2][8192];
  const int tid = threadIdx.x;
  const int wave = tid >> 6, lane = tid & 63;
  const int lo = lane & 15, hi = lane >> 4;
  const int rowbase = (BM == 64) ? 0 : ((wave >> 1) * 64);
  const int colbase = (BM == 64) ? (wave * 32) : ((wave & 1) * 64);
  A += (size_t)bz * (size_t)bA;
  B += (size_t)bz * (size_t)bB;
  const int srow = lane >> 3;                        // 0..7 (also row&7)
  const int scol = (((lane & 7) ^ srow) * 8);        // inverse-swizzled source col
  const int rsw = lo & 7;                            // read-side row&7

  auto stage = [&](int k0, int buf) {
#pragma unroll
    for (int i = 0; i < PER; ++i) {
      const int blk = wave * PER + i;
      if (blk < ACH) {
        const int row = blk * 8 + srow;
        gload16(A + (m0 + row) * (size_t)lda + k0 + scol, &As[buf][blk * 512]);
      } else {
        const int j = blk - ACH;
        const int row = j * 8 + srow;
        gload16(B + (n0 + row) * (size_t)ldb + k0 + scol, &Bs[buf][j * 512]);
      }
    }
  };

  f32x4 acc[4][NFR] = {};
  stage(0, 0);
  int cur = 0;
  for (int k0 = 0; k0 < Keff; k0 += 64) {
    __syncthreads();
    if (k0 + 64 < Keff) stage(k0 + 64, cur ^ 1);
#pragma unroll
    for (int kk = 0; kk < 2; ++kk) {
      const int ch = (((kk << 2) + hi) ^ rsw) << 3;
      bf16x8 af[4], bfr[NFR];
#pragma unroll
      for (int m = 0; m < 4; ++m)
        af[m] = *(const bf16x8*)&As[cur][(rowbase + m * 16 + lo) * 64 + ch];
#pragma unroll
      for (int n = 0; n < NFR; ++n)
        bfr[n] = *(const bf16x8*)&Bs[cur][(colbase + n * 16 + lo) * 64 + ch];
#pragma unroll
      for (int m = 0; m < 4; ++m)
#pragma unroll
        for (int n = 0; n < NFR; ++n)
          acc[m][n] = __builtin_amdgcn_mfma_f32_16x16x32_bf16(af[m], bfr[n], acc[m][n], 0, 0, 0);
    }
    cur ^= 1;
  }
  float* Cf = (float*)Cv;
  bf16* Cb = (bf16*)Cv;
  const size_t cbase = (size_t)bz * (size_t)bC;
#pragma unroll
  for (int m = 0; m < 4; ++m) {
    const size_t row = m0 + rowbase + m * 16 + hi * 4;
#pragma unroll
    for (int n = 0; n < NFR; ++n) {
      const int col = (int)n0 + colbase + n * 16 + lo;
      if (col < Nreal) {
        const float bv = BIAS ? bias[col] : 0.0f;
#pragma unroll
        for (int j = 0; j < 4; ++j) {
          const float v = acc[m][n][j] + bv;
          const size_t off = cbase + (row + j) * (size_t)ldc + col;
          if (BF16OUT) Cb[off] = __float2bfloat16(v);
          else         Cf[off] = v;
        }
      }
    }
  }
}

// ---------------------------------------------------------------------------
extern "C" void kernel_launch(void* const* d_in, const int* in_sizes, int n_in,
                              void* d_out, int out_size, void* d_ws, size_t ws_size,
                              hipStream_t stream) {
  const float* x       = (const float*)d_in[0];
  const float* wq_a_w  = (const float*)d_in[1];
  const float* wq_a_b  = (const float*)d_in[2];
  const float* q_norm  = (const float*)d_in[3];
  const float* wq_b_w  = (const float*)d_in[4];
  const float* wq_b_b  = (const float*)d_in[5];
  const float* wkv_a_w = (const float*)d_in[6];
  const float* wkv_a_b = (const float*)d_in[7];
  const float* kv_norm = (const float*)d_in[8];
  const float* wkv_b_w = (const float*)d_in[9];
  const float* wo_w    = (const float*)d_in[10];
  const float* wo_bias = (const float*)d_in[11];
  float* out = (float*)d_out;

  char* base = (char*)d_ws;
  // Transient staging region (all dead before attention):
  bf16*  xb   = (bf16*)(base + 0);          //  8,388,608
  bf16*  wqa  = (bf16*)(base + 8388608);    //  6,291,456
  bf16*  wqb  = (bf16*)(base + 14680064);   //  9,437,184
  bf16*  wkva = (bf16*)(base + 24117248);   //  2,621,440
  bf16*  wkvb = (bf16*)(base + 26738688);   //  4,194,304
  bf16*  qa   = (bf16*)(base + 30932992);   //  6,291,456
  bf16*  qn   = (bf16*)(base + 37224448);   //  6,291,456
  float* kvf  = (float*)(base + 43515904);  //  5,242,880
  bf16*  kvn  = (bf16*)(base + 48758784);   //  2,097,152
  // Persistent buffers:
  char* q = base + 134217728;
  bf16* qv    = (bf16*)(q);            q += 12582912;  // 2048x3072
  bf16* Kh    = (bf16*)(q);            q += 12582912;  // 16x2048x192
  bf16* V2T   = (bf16*)(q);            q += 8388608;   // 16x128x2048
  bf16* wob   = (bf16*)(q);            q += 8388608;   // 2048x2048
  bf16* oabs  = (bf16*)(q);            q += 8388608;   // 2048x2048
  float* oP   = (float*)(q);           q += 33554432;  // 2x16x2048x128 f32
  float* mP   = (float*)(q);           q += 262144;    // 2x16x2048 f32
  float* lP   = (float*)(q);           q += 262144;    // 2x16x2048 f32

  // all fp32->bf16 converts in one launch
  cvt_all<<<dim3(2048), 256, 0, stream>>>(x, wq_a_w, wq_b_w, wkv_a_w, wkv_b_w, wo_w,
                                          xb, wqa, wqb, wkva, wkvb, wob);

  // q_a = rmsnorm(x @ wq_a^T + b)
  gemm_bt<true, true, 64><<<dim3(12, 32, 1), 256, 0, stream>>>(
      xb, wqa, wq_a_b, qa, 2048, 2048, 1536, 2048, 1536, 0, 0, 0, 0);
  rmsnorm_bf16<<<2048, 256, 0, stream>>>(qa, q_norm, qn, 1536);
  // q = qn @ wq_b^T + b -> qv [2048][3072] (16 heads x 192)
  gemm_bt<true, true, 128><<<dim3(24, 16, 1), 256, 0, stream>>>(
      qn, wqb, wq_b_b, qv, 1536, 1536, 3072, 1536, 3072, 0, 0, 0, 0);
  q_rope<<<2048, 256, 0, stream>>>(qv);
  // kv_full = x @ wkv_a^T + b -> fp32 [2048][640] (576 valid)
  gemm_bt<true, false, 64><<<dim3(5, 32, 1), 256, 0, stream>>>(
      xb, wkva, wkv_a_b, kvf, 2048, 2048, 640, 2048, 576, 0, 0, 0, 0);
  kv_post<<<2048, 256, 0, stream>>>(kvf, kv_norm, kvn, Kh);
  // K_h nope: Kh[h][t][0..128) = kvn[t] . wkvb[h*256+d][:]  (d<128)
  gemm_bt<false, true, 64><<<dim3(1, 32, 16), 256, 0, stream>>>(
      kvn, wkvb, nullptr, Kh, 512, 512, 192, 512, 128,
      0, 256ll * 512, 2048ll * 192, 0);
  // V2T[h][d][t] = wkvb[h*256+128+d][:] . kvn[t][:]
  gemm_bt<false, true, 64><<<dim3(16, 2, 16), 256, 0, stream>>>(
      wkvb + 128ull * 512, kvn, nullptr, V2T, 512, 512, 2048, 512, 2048,
      256ll * 512, 0, 128ll * 2048, 0);

  // ---- split-K fused flash attention -> partials, then combine -> oabs
  attn_split<<<dim3(1024), 256, 0, stream>>>(qv, Kh, V2T, oP, mP, lP);
  attn_combine<<<dim3(1024, 16), 256, 0, stream>>>(oP, mP, lP, oabs);

  // final: out = oabs @ wo^T + b (fp32 out)
  gemm_bt<true, false, 64><<<dim3(16, 32, 1), 256, 0, stream>>>(
      oabs, wob, wo_bias, out, 2048, 2048, 2048, 2048, 2048, 0, 0, 0, 0);
}